// Round 14
// baseline (376.720 us; speedup 1.0000x reference)
//
#include <hip/hip_runtime.h>
#include <hip/hip_cooperative_groups.h>

namespace cg = cooperative_groups;

// Problem constants (from reference)
constexpr int B_  = 16;
constexpr int NV_ = 10475;
constexpr int F_  = 20908;
constexpr int P_  = F_ * 8;              // 167264 pairs per batch
constexpr float LINEAR_MAX_ = 1000.0f;

constexpr int PB_      = 82;             // blocks per batch (82*256 >= F_; 82*256*8 >= P_)
constexpr int NBLK_    = 16 * PB_;       // 1312 blocks total (co-resident: VGPR/LDS light)
constexpr int PSTRIDE_ = PB_ * 256;      // 20992 pair stride per k-step

// d_ws layout:
//   tbl  : 64 B per (b,f) record = 21.4 MB   (offset 0)
//   part : float[B_*PB_]                      (offset 21.4 MB)
// Record (b,f): [0]{n.xyz, c·n} [1]{v0.xyz,v1.x} [2]{v1.yz,v2.xy} [3]{v2.z,-,-,-}

// XCD b-locality swizzle (consecutive bids round-robin the 8 XCDs): each XCD
// serves 2 batches -> per-XCD table slice 2.7 MB, L2-resident. Heuristic only;
// correctness never depends on it.
__device__ __forceinline__ void swz(int bid, int& b, int& px) {
    const int xcd = bid & 7;
    const int j   = bid >> 3;
    b  = xcd + ((j & 1) << 3);
    px = j >> 1;
}

__global__ __launch_bounds__(256) void fused_pen_kernel(
    const float* __restrict__ v,        // (B, NV, 3)
    const int*   __restrict__ faces,    // (F, 3)
    const int2*  __restrict__ coll,     // (B, P)
    float4*      __restrict__ tbl,
    float*       __restrict__ part,     // (B, PB_)
    float*       __restrict__ out)      // (B,)
{
    cg::grid_group grid = cg::this_grid();

    __shared__ float4 lds4[1024];       // 256 records * 4 float4 = 16 KB
    __shared__ float  wsum[4];

    int b, px; swz(blockIdx.x, b, px);
    const int t = threadIdx.x;

    // ---------------- Phase A: build 64B face records ----------------
    {
        const int f0 = px * 256;
        const int f  = f0 + t;
        const int fc = (f < F_) ? f : 0;          // clamp tail (no OOB read)

        const float* __restrict__ vb = v + (size_t)b * (NV_ * 3);
        const int i0 = faces[fc * 3 + 0] * 3;
        const int i1 = faces[fc * 3 + 1] * 3;
        const int i2 = faces[fc * 3 + 2] * 3;

        const float v0x = vb[i0 + 0], v0y = vb[i0 + 1], v0z = vb[i0 + 2];
        const float v1x = vb[i1 + 0], v1y = vb[i1 + 1], v1z = vb[i1 + 2];
        const float v2x = vb[i2 + 0], v2y = vb[i2 + 1], v2z = vb[i2 + 2];

        const float third = 1.0f / 3.0f;
        const float cx = (v0x + v1x + v2x) * third;
        const float cy = (v0y + v1y + v2y) * third;
        const float cz = (v0z + v1z + v2z) * third;

        const float e1x = v1x - v0x, e1y = v1y - v0y, e1z = v1z - v0z;
        const float e2x = v2x - v0x, e2y = v2y - v0y, e2z = v2z - v0z;
        float nx = e1y * e2z - e1z * e2y;
        float ny = e1z * e2x - e1x * e2z;
        float nz = e1x * e2y - e1y * e2x;
        const float inv = 1.0f / (sqrtf(nx * nx + ny * ny + nz * nz) + 1e-12f);
        nx *= inv; ny *= inv; nz *= inv;

        lds4[t * 4 + 0] = make_float4(nx, ny, nz, cx * nx + cy * ny + cz * nz);
        lds4[t * 4 + 1] = make_float4(v0x, v0y, v0z, v1x);
        lds4[t * 4 + 2] = make_float4(v1y, v1z, v2x, v2y);
        lds4[t * 4 + 3] = make_float4(v2z, 0.0f, 0.0f, 0.0f);
        __syncthreads();

        // Coalesced write-out; guard tail so batch b never writes past its region.
        const int vrec  = F_ - f0;
        const int limit = ((vrec < 256) ? vrec : 256) * 4;
        float4* dst = tbl + ((size_t)b * F_ + f0) * 4;
        #pragma unroll
        for (int j = 0; j < 4; ++j) {
            const int e = j * 256 + t;
            if (e < limit) dst[e] = lds4[e];
        }
    }

    grid.sync();

    // ---------------- Phase B: pairs (8 per thread, coalesced int2) ----------------
    {
        const int2*   __restrict__ cb = coll + (size_t)b * P_;
        const float4* __restrict__ bt = tbl + (size_t)b * F_ * 4;
        const int p0 = px * 256 + t;

        float psi2 = 0.0f;

        #pragma unroll
        for (int k = 0; k < 8; ++k) {
            const int p = p0 + k * PSTRIDE_;
            if (p < P_) {
                const int2 pr = cb[p];
                const float m = ((pr.x | pr.y) >= 0) ? 1.0f : 0.0f;
                const int fR = (pr.y > 0) ? pr.y : 0;   // receiver
                const int fI = (pr.x > 0) ? pr.x : 0;   // intruder

                const float4 nd = bt[fR * 4 + 0];
                const float4 L0 = bt[fI * 4 + 1];
                const float4 L1 = bt[fI * 4 + 2];
                const float4 L2 = bt[fI * 4 + 3];

                float s = 0.0f;
                float t0 = nd.w - (L0.x * nd.x + L0.y * nd.y + L0.z * nd.z);
                t0 = fminf(fmaxf(t0, 0.0f), LINEAR_MAX_);
                s = fmaf(t0, t0, s);
                float t1 = nd.w - (L0.w * nd.x + L1.x * nd.y + L1.y * nd.z);
                t1 = fminf(fmaxf(t1, 0.0f), LINEAR_MAX_);
                s = fmaf(t1, t1, s);
                float t2 = nd.w - (L1.z * nd.x + L1.w * nd.y + L2.x * nd.z);
                t2 = fminf(fmaxf(t2, 0.0f), LINEAR_MAX_);
                s = fmaf(t2, t2, s);

                psi2 = fmaf(m, s, psi2);
            }
        }

        #pragma unroll
        for (int off = 32; off > 0; off >>= 1)
            psi2 += __shfl_down(psi2, off, 64);

        if ((t & 63) == 0) wsum[t >> 6] = psi2;
        __syncthreads();

        if (t == 0)
            part[b * PB_ + px] = wsum[0] + wsum[1] + wsum[2] + wsum[3];
    }

    grid.sync();

    // ---------------- Phase C: 16 blocks reduce partials -> out ----------------
    if (px == 0) {
        float s = (t < PB_) ? part[b * PB_ + t] : 0.0f;

        #pragma unroll
        for (int off = 32; off > 0; off >>= 1)
            s += __shfl_down(s, off, 64);

        __syncthreads();                 // wsum reuse hazard guard
        if ((t & 63) == 0) wsum[t >> 6] = s;
        __syncthreads();

        if (t == 0) out[b] = wsum[0] + wsum[1] + wsum[2] + wsum[3];
    }
}

extern "C" void kernel_launch(void* const* d_in, const int* in_sizes, int n_in,
                              void* d_out, int out_size, void* d_ws, size_t ws_size,
                              hipStream_t stream) {
    const float* v     = (const float*)d_in[0];
    const int*   faces = (const int*)d_in[1];
    const int2*  coll  = (const int2*)d_in[2];
    float* out = (float*)d_out;

    float4* tbl  = (float4*)d_ws;
    float*  part = (float*)((char*)d_ws + (size_t)B_ * F_ * 64);

    void* args[] = { (void*)&v, (void*)&faces, (void*)&coll,
                     (void*)&tbl, (void*)&part, (void*)&out };
    hipLaunchCooperativeKernel((const void*)fused_pen_kernel,
                               dim3(NBLK_), dim3(256), args, 0, stream);
}

// Round 15
// 170.936 us; speedup vs baseline: 2.2039x; 2.2039x over previous
//
#include <hip/hip_runtime.h>

// Problem constants (from reference)
constexpr int B_  = 16;
constexpr int NV_ = 10475;
constexpr int F_  = 20908;
constexpr int P_  = F_ * 8;              // 167264 pairs per batch
constexpr float LINEAR_MAX_ = 1000.0f;

constexpr int REC_PB_  = 82;             // face-record blocks per batch (82*256 >= F_)
constexpr int PAIR_PB_ = 164;            // pair blocks per batch (164*256*4 >= P_)
constexpr int QSTRIDE_ = PAIR_PB_ * 256; // 41984, per-thread pair stride

// d_ws layout:
//   tbl  : 64 B per (b,f) record = 21.4 MB     (offset 0)
//   part : float[B_*PAIR_PB_]                   (offset 21.4 MB)
//   tick : int[B_] last-block tickets           (after part)
// Record (b,f): [0]{n.xyz, c·n} [1]{v0.xyz,v1.x} [2]{v1.yz,v2.xy} [3]{v2.z,-,-,-}

// XCD b-locality swizzle (consecutive bids round-robin the 8 XCDs): each XCD
// serves 2 batches -> per-XCD table slice 2.7 MB, L2-resident. Heuristic only;
// correctness never depends on it.
__device__ __forceinline__ void swz(int bid, int& b, int& px) {
    const int xcd = bid & 7;
    const int j   = bid >> 3;
    b  = xcd + ((j & 1) << 3);
    px = j >> 1;
}

// Pass 1: build 64B records; stage in LDS (padded stride 5 -> no 4-way bank
// conflict), write coalesced. Also zeroes the per-batch ticket counters that
// live in poisoned d_ws (stream order guarantees pen sees zeros).
__global__ __launch_bounds__(256) void face_rec_kernel(
    const float* __restrict__ v,        // (B, NV, 3)
    const int*   __restrict__ faces,    // (F, 3)
    float4*      __restrict__ tbl,
    int*         __restrict__ tick)     // (B,)
{
    __shared__ float4 lds4[256 * 5];    // padded: record r word j at [r*5+j], 20 KB

    int b, px; swz(blockIdx.x, b, px);
    const int t  = threadIdx.x;

    if (blockIdx.x == 0 && t < B_) tick[t] = 0;

    const int f0 = px * 256;
    const int f  = f0 + t;
    const int fc = (f < F_) ? f : 0;    // clamp tail (no OOB read)

    const float* __restrict__ vb = v + (size_t)b * (NV_ * 3);
    const int i0 = faces[fc * 3 + 0] * 3;
    const int i1 = faces[fc * 3 + 1] * 3;
    const int i2 = faces[fc * 3 + 2] * 3;

    const float v0x = vb[i0 + 0], v0y = vb[i0 + 1], v0z = vb[i0 + 2];
    const float v1x = vb[i1 + 0], v1y = vb[i1 + 1], v1z = vb[i1 + 2];
    const float v2x = vb[i2 + 0], v2y = vb[i2 + 1], v2z = vb[i2 + 2];

    const float third = 1.0f / 3.0f;
    const float cx = (v0x + v1x + v2x) * third;
    const float cy = (v0y + v1y + v2y) * third;
    const float cz = (v0z + v1z + v2z) * third;

    const float e1x = v1x - v0x, e1y = v1y - v0y, e1z = v1z - v0z;
    const float e2x = v2x - v0x, e2y = v2y - v0y, e2z = v2z - v0z;
    float nx = e1y * e2z - e1z * e2y;
    float ny = e1z * e2x - e1x * e2z;
    float nz = e1x * e2y - e1y * e2x;
    const float inv = 1.0f / (sqrtf(nx * nx + ny * ny + nz * nz) + 1e-12f);
    nx *= inv; ny *= inv; nz *= inv;

    lds4[t * 5 + 0] = make_float4(nx, ny, nz, cx * nx + cy * ny + cz * nz);
    lds4[t * 5 + 1] = make_float4(v0x, v0y, v0z, v1x);
    lds4[t * 5 + 2] = make_float4(v1y, v1z, v2x, v2y);
    lds4[t * 5 + 3] = make_float4(v2z, 0.0f, 0.0f, 0.0f);
    __syncthreads();

    // Coalesced write-out; guard tail so batch b never writes past its region.
    const int vrec  = F_ - f0;
    const int limit = ((vrec < 256) ? vrec : 256) * 4;
    float4* dst = tbl + ((size_t)b * F_ + f0) * 4;
    #pragma unroll
    for (int j = 0; j < 4; ++j) {
        const int e = j * 256 + t;
        if (e < limit) dst[e] = lds4[(e >> 2) * 5 + (e & 3)];
    }
}

// Pass 2: 4 pairs/thread (coalesced int2). Per valid pair: 4 scattered float4
// loads in 2 cache lines. No contended atomics for the sum: one partial per
// block + last-block-per-batch reduces (agent-scope atomics, cross-XCD safe).
__global__ __launch_bounds__(256) void pen_pairs_kernel(
    const int2*   __restrict__ coll,    // (B, P)
    const float4* __restrict__ tbl,
    float*        __restrict__ part,    // (B, PAIR_PB_)
    int*          __restrict__ tick,    // (B,)
    float*        __restrict__ out)     // (B,)
{
    int b, px; swz(blockIdx.x, b, px);
    const int t = threadIdx.x;
    const int p0 = px * 256 + t;

    const int2*   __restrict__ cb = coll + (size_t)b * P_;
    const float4* __restrict__ bt = tbl + (size_t)b * F_ * 4;

    float psi2 = 0.0f;

    #pragma unroll
    for (int k = 0; k < 4; ++k) {
        const int p = p0 + k * QSTRIDE_;
        if (p < P_) {
            const int2 pr = cb[p];
            const float m = ((pr.x | pr.y) >= 0) ? 1.0f : 0.0f;
            const int fR = (pr.y > 0) ? pr.y : 0;   // receiver
            const int fI = (pr.x > 0) ? pr.x : 0;   // intruder

            const float4 nd = bt[fR * 4 + 0];
            const float4 L0 = bt[fI * 4 + 1];
            const float4 L1 = bt[fI * 4 + 2];
            const float4 L2 = bt[fI * 4 + 3];

            float s = 0.0f;
            float t0 = nd.w - (L0.x * nd.x + L0.y * nd.y + L0.z * nd.z);
            t0 = fminf(fmaxf(t0, 0.0f), LINEAR_MAX_);
            s = fmaf(t0, t0, s);
            float t1 = nd.w - (L0.w * nd.x + L1.x * nd.y + L1.y * nd.z);
            t1 = fminf(fmaxf(t1, 0.0f), LINEAR_MAX_);
            s = fmaf(t1, t1, s);
            float t2 = nd.w - (L1.z * nd.x + L1.w * nd.y + L2.x * nd.z);
            t2 = fminf(fmaxf(t2, 0.0f), LINEAR_MAX_);
            s = fmaf(t2, t2, s);

            psi2 = fmaf(m, s, psi2);
        }
    }

    #pragma unroll
    for (int off = 32; off > 0; off >>= 1)
        psi2 += __shfl_down(psi2, off, 64);

    __shared__ float wsum[4];
    __shared__ int   lastflag;
    if ((t & 63) == 0) wsum[t >> 6] = psi2;
    __syncthreads();

    if (t == 0) {
        const float blocksum = wsum[0] + wsum[1] + wsum[2] + wsum[3];
        __hip_atomic_store(&part[b * PAIR_PB_ + px], blocksum,
                           __ATOMIC_RELEASE, __HIP_MEMORY_SCOPE_AGENT);
        const int prev = __hip_atomic_fetch_add(&tick[b], 1,
                           __ATOMIC_ACQ_REL, __HIP_MEMORY_SCOPE_AGENT);
        lastflag = (prev == PAIR_PB_ - 1);
    }
    __syncthreads();

    if (lastflag) {                     // exactly one block per batch
        float s = 0.0f;
        if (t < PAIR_PB_)
            s = __hip_atomic_load(&part[b * PAIR_PB_ + t],
                                  __ATOMIC_ACQUIRE, __HIP_MEMORY_SCOPE_AGENT);

        #pragma unroll
        for (int off = 32; off > 0; off >>= 1)
            s += __shfl_down(s, off, 64);

        __syncthreads();                // wsum reuse guard
        if ((t & 63) == 0) wsum[t >> 6] = s;
        __syncthreads();

        if (t == 0) out[b] = wsum[0] + wsum[1] + wsum[2] + wsum[3];
    }
}

extern "C" void kernel_launch(void* const* d_in, const int* in_sizes, int n_in,
                              void* d_out, int out_size, void* d_ws, size_t ws_size,
                              hipStream_t stream) {
    const float* v     = (const float*)d_in[0];
    const int*   faces = (const int*)d_in[1];
    const int2*  coll  = (const int2*)d_in[2];
    float* out = (float*)d_out;

    char* ws = (char*)d_ws;
    float4* tbl  = (float4*)ws;   ws += (size_t)B_ * F_ * 64;
    float*  part = (float*)ws;    ws += (size_t)B_ * PAIR_PB_ * sizeof(float);
    int*    tick = (int*)ws;

    dim3 block(256);
    face_rec_kernel <<<dim3(16 * REC_PB_),  block, 0, stream>>>(v, faces, tbl, tick);      // 1312
    pen_pairs_kernel<<<dim3(16 * PAIR_PB_), block, 0, stream>>>(coll, tbl, part, tick, out); // 2624
}

// Round 17
// 90.311 us; speedup vs baseline: 4.1714x; 1.8927x over previous
//
#include <hip/hip_runtime.h>

// Problem constants (from reference)
constexpr int B_  = 16;
constexpr int NV_ = 10475;
constexpr int F_  = 20908;
constexpr int P_  = F_ * 8;              // 167264 pairs per batch
constexpr float LINEAR_MAX_ = 1000.0f;

constexpr int REC_PB_  = 82;             // face-record blocks per batch (82*256 >= F_)
constexpr int PAIR_PB_ = 164;            // pair blocks per batch (164*256*4 >= P_)
constexpr int QSTRIDE_ = PAIR_PB_ * 256; // 41984, per-thread pair stride

// d_ws layout:
//   tbl  : 64 B per (b,f) record = 21.4 MB   (offset 0)
//   part : float[B_*PAIR_PB_]                 (offset 21.4 MB)
// Record (b,f): [0]{n.xyz, c·n} [1]{v0.xyz,v1.x} [2]{v1.yz,v2.xy} [3]{v2.z,-,-,-}
//
// Sync discipline (measured): kernel boundaries only. grid.sync() cost ~130 µs
// (R14) and ticket+acq/rel atomics ~100 µs (R15) on this chip — never again.

// XCD b-locality swizzle (consecutive bids round-robin the 8 XCDs): each XCD
// serves 2 batches -> per-XCD table slice 2.7 MB, L2-resident. Heuristic only;
// correctness never depends on it.
__device__ __forceinline__ void swz(int bid, int& b, int& px) {
    const int xcd = bid & 7;
    const int j   = bid >> 3;
    b  = xcd + ((j & 1) << 3);
    px = j >> 1;
}

// Pass 1: build 64B records. Stage in LDS with stride-5 padding (R14 profile
// showed 503K bank conflicts at stride-4), then write coalesced
// (4 sequential-line float4 stores per wave instead of 64-line scattered).
__global__ __launch_bounds__(256) void face_rec_kernel(
    const float* __restrict__ v,        // (B, NV, 3)
    const int*   __restrict__ faces,    // (F, 3)
    float4*      __restrict__ tbl)
{
    __shared__ float4 lds4[256 * 5];    // record r, word j at [r*5+j]; 20 KB

    int b, px; swz(blockIdx.x, b, px);
    const int t  = threadIdx.x;
    const int f0 = px * 256;
    const int f  = f0 + t;
    const int fc = (f < F_) ? f : 0;    // clamp tail (no OOB read)

    const float* __restrict__ vb = v + (size_t)b * (NV_ * 3);
    const int i0 = faces[fc * 3 + 0] * 3;
    const int i1 = faces[fc * 3 + 1] * 3;
    const int i2 = faces[fc * 3 + 2] * 3;

    const float v0x = vb[i0 + 0], v0y = vb[i0 + 1], v0z = vb[i0 + 2];
    const float v1x = vb[i1 + 0], v1y = vb[i1 + 1], v1z = vb[i1 + 2];
    const float v2x = vb[i2 + 0], v2y = vb[i2 + 1], v2z = vb[i2 + 2];

    const float third = 1.0f / 3.0f;
    const float cx = (v0x + v1x + v2x) * third;
    const float cy = (v0y + v1y + v2y) * third;
    const float cz = (v0z + v1z + v2z) * third;

    const float e1x = v1x - v0x, e1y = v1y - v0y, e1z = v1z - v0z;
    const float e2x = v2x - v0x, e2y = v2y - v0y, e2z = v2z - v0z;
    float nx = e1y * e2z - e1z * e2y;
    float ny = e1z * e2x - e1x * e2z;
    float nz = e1x * e2y - e1y * e2x;
    const float inv = 1.0f / (sqrtf(nx * nx + ny * ny + nz * nz) + 1e-12f);
    nx *= inv; ny *= inv; nz *= inv;

    lds4[t * 5 + 0] = make_float4(nx, ny, nz, cx * nx + cy * ny + cz * nz);
    lds4[t * 5 + 1] = make_float4(v0x, v0y, v0z, v1x);
    lds4[t * 5 + 2] = make_float4(v1y, v1z, v2x, v2y);
    lds4[t * 5 + 3] = make_float4(v2z, 0.0f, 0.0f, 0.0f);
    __syncthreads();

    // Coalesced write-out; guard tail so batch b never writes past its region.
    const int vrec  = F_ - f0;
    const int limit = ((vrec < 256) ? vrec : 256) * 4;
    float4* dst = tbl + ((size_t)b * F_ + f0) * 4;
    #pragma unroll
    for (int j = 0; j < 4; ++j) {
        const int e = j * 256 + t;
        if (e < limit) dst[e] = lds4[(e >> 2) * 5 + (e & 3)];
    }
}

// Pass 2: 4 pairs per thread (coalesced int2). Per valid pair: 4 scattered
// float4 loads touching 2 cache lines. No atomics: one plain store per block.
__global__ __launch_bounds__(256) void pen_pairs_kernel(
    const int2*   __restrict__ coll,    // (B, P)
    const float4* __restrict__ tbl,
    float*        __restrict__ part)    // (B, PAIR_PB_)
{
    int b, px; swz(blockIdx.x, b, px);
    const int p0 = px * 256 + threadIdx.x;

    const int2*   __restrict__ cb = coll + (size_t)b * P_;
    const float4* __restrict__ bt = tbl + (size_t)b * F_ * 4;

    float psi2 = 0.0f;

    #pragma unroll
    for (int k = 0; k < 4; ++k) {
        const int p = p0 + k * QSTRIDE_;
        if (p < P_) {
            const int2 pr = cb[p];
            const float m = ((pr.x | pr.y) >= 0) ? 1.0f : 0.0f;
            const int fR = (pr.y > 0) ? pr.y : 0;   // receiver
            const int fI = (pr.x > 0) ? pr.x : 0;   // intruder

            const float4 nd = bt[fR * 4 + 0];
            const float4 L0 = bt[fI * 4 + 1];
            const float4 L1 = bt[fI * 4 + 2];
            const float4 L2 = bt[fI * 4 + 3];

            float s = 0.0f;
            float t0 = nd.w - (L0.x * nd.x + L0.y * nd.y + L0.z * nd.z);
            t0 = fminf(fmaxf(t0, 0.0f), LINEAR_MAX_);
            s = fmaf(t0, t0, s);
            float t1 = nd.w - (L0.w * nd.x + L1.x * nd.y + L1.y * nd.z);
            t1 = fminf(fmaxf(t1, 0.0f), LINEAR_MAX_);
            s = fmaf(t1, t1, s);
            float t2 = nd.w - (L1.z * nd.x + L1.w * nd.y + L2.x * nd.z);
            t2 = fminf(fmaxf(t2, 0.0f), LINEAR_MAX_);
            s = fmaf(t2, t2, s);

            psi2 = fmaf(m, s, psi2);
        }
    }

    #pragma unroll
    for (int off = 32; off > 0; off >>= 1)
        psi2 += __shfl_down(psi2, off, 64);

    __shared__ float wsum[4];
    const int lane = threadIdx.x & 63;
    const int wid  = threadIdx.x >> 6;
    if (lane == 0) wsum[wid] = psi2;
    __syncthreads();

    if (threadIdx.x == 0)
        part[b * PAIR_PB_ + px] = wsum[0] + wsum[1] + wsum[2] + wsum[3];
}

// Pass 3: block b sums its 164 partials, writes out[b] (overwrites poison).
__global__ __launch_bounds__(256) void final_reduce_kernel(
    const float* __restrict__ part,     // (B, PAIR_PB_)
    float*       __restrict__ out)      // (B,)
{
    const int b = blockIdx.x;
    const int t = threadIdx.x;

    float s = (t < PAIR_PB_) ? part[b * PAIR_PB_ + t] : 0.0f;

    #pragma unroll
    for (int off = 32; off > 0; off >>= 1)
        s += __shfl_down(s, off, 64);

    __shared__ float wsum[4];
    if ((t & 63) == 0) wsum[t >> 6] = s;
    __syncthreads();

    if (t == 0) out[b] = wsum[0] + wsum[1] + wsum[2] + wsum[3];
}

extern "C" void kernel_launch(void* const* d_in, const int* in_sizes, int n_in,
                              void* d_out, int out_size, void* d_ws, size_t ws_size,
                              hipStream_t stream) {
    const float* v     = (const float*)d_in[0];
    const int*   faces = (const int*)d_in[1];
    const int2*  coll  = (const int2*)d_in[2];
    float* out = (float*)d_out;

    float4* tbl  = (float4*)d_ws;
    float*  part = (float*)((char*)d_ws + (size_t)B_ * F_ * 64);

    dim3 block(256);
    face_rec_kernel   <<<dim3(16 * REC_PB_),  block, 0, stream>>>(v, faces, tbl);   // 1312
    pen_pairs_kernel  <<<dim3(16 * PAIR_PB_), block, 0, stream>>>(coll, tbl, part); // 2624
    final_reduce_kernel<<<dim3(B_),           block, 0, stream>>>(part, out);
}